// Round 1
// baseline (121.945 us; speedup 1.0000x reference)
//
#include <hip/hip_runtime.h>
#include <math.h>

#define D_DIM 256
#define K_BINS 32

static constexpr float BOUND = 3.0f;
static constexpr float MIN_BIN_W = 1e-3f;
static constexpr float MIN_BIN_H = 1e-3f;
static constexpr float MIN_DERIV = 1e-3f;
static constexpr float MIN_LAMBDA = 0.025f;
static constexpr float EPS_ = 1e-6f;

struct BinParam {
  float icw, inv_iw, il, ya;    // float4 #0
  float wc, wcyc, wb, wbyb;     // float4 #1
  float llo, lhi, pad0, pad1;   // float2 used (llo,lhi); padded to 48 B
};

__device__ __forceinline__ float softplusf(float x) {
  // jax.nn.softplus: max(x,0) + log1p(exp(-|x|))
  return fmaxf(x, 0.0f) + log1pf(expf(-fabsf(x)));
}

__global__ void spline_precompute(const float* __restrict__ uw,
                                  const float* __restrict__ uh,
                                  const float* __restrict__ ud,
                                  const float* __restrict__ ul,
                                  BinParam* __restrict__ tbl,
                                  float* __restrict__ cw_g) {
  int d = blockIdx.x * blockDim.x + threadIdx.x;
  if (d >= D_DIM) return;
  const float* uwd = uw + d * K_BINS;
  const float* uhd = uh + d * K_BINS;
  const float* udd = ud + d * (K_BINS - 1);
  const float* uld = ul + d * K_BINS;

  // softmax denominators
  float wmax = -INFINITY, hmax = -INFINITY;
  for (int k = 0; k < K_BINS; ++k) {
    wmax = fmaxf(wmax, uwd[k]);
    hmax = fmaxf(hmax, uhd[k]);
  }
  float wsum = 0.f, hsum = 0.f;
  for (int k = 0; k < K_BINS; ++k) {
    wsum += expf(uwd[k] - wmax);
    hsum += expf(uhd[k] - hmax);
  }
  float winv = 1.f / wsum, hinv = 1.f / hsum;

  const float scale = 2.f * BOUND;
  float cumw = 0.f, cumh = 0.f;
  float cw_lo = -BOUND, ch_lo = -BOUND;
  float d0 = 1.f;
  cw_g[0 * D_DIM + d] = -BOUND;

  for (int k = 0; k < K_BINS; ++k) {
    float fw = expf(uwd[k] - wmax) * winv;
    float fh = expf(uhd[k] - hmax) * hinv;
    cumw += MIN_BIN_W + (1.f - MIN_BIN_W * (float)K_BINS) * fw;
    cumh += MIN_BIN_H + (1.f - MIN_BIN_H * (float)K_BINS) * fh;
    float cw_hi = (k == K_BINS - 1) ? BOUND : (scale * cumw - BOUND);
    float ch_hi = (k == K_BINS - 1) ? BOUND : (scale * cumh - BOUND);
    cw_g[(k + 1) * D_DIM + d] = cw_hi;

    float iw = cw_hi - cw_lo;
    float ih = ch_hi - ch_lo;
    float delta = ih / iw;
    float d1 = (k == K_BINS - 1) ? 1.f : (MIN_DERIV + softplusf(udd[k]));
    float sg = 1.f / (1.f + expf(-uld[k]));
    float lam = MIN_LAMBDA + (1.f - 2.f * MIN_LAMBDA) * sg;

    float wb = sqrtf(d0 / d1);
    float wc = (lam * d0 + (1.f - lam) * wb * d1) / delta;
    float ya = ch_lo;
    float yb = ih + ya;  // match reference's ih + ich
    float yc = ((1.f - lam) * ya + lam * wb * yb) / ((1.f - lam) + lam * wb);

    BinParam p;
    p.icw = cw_lo;
    p.inv_iw = 1.f / iw;
    p.il = lam;
    p.ya = ya;
    p.wc = wc;
    p.wcyc = wc * yc;
    p.wb = wb;
    p.wbyb = wb * yb;
    p.llo = logf(wc * lam * (yc - ya) / iw);
    p.lhi = logf(wb * wc * (1.f - lam) * (yb - yc) / iw);
    p.pad0 = 0.f;
    p.pad1 = 0.f;
    tbl[d * K_BINS + k] = p;

    cw_lo = cw_hi;
    ch_lo = ch_hi;
    d0 = d1;
  }
}

__global__ __launch_bounds__(256) void spline_main(
    const float* __restrict__ x,
    const BinParam* __restrict__ tbl,
    const float* __restrict__ cw_g,
    float* __restrict__ uout,
    float* __restrict__ ldout,
    int nrows) {
  __shared__ float lcw[(K_BINS + 1) * D_DIM];  // 33*256*4 = 33792 B, layout [k][d]
  int t = threadIdx.x;
#pragma unroll
  for (int k = 0; k < K_BINS + 1; ++k) lcw[k * D_DIM + t] = cw_g[k * D_DIM + t];
  __syncthreads();

  int lane = t & 63;
  int wid = t >> 6;  // wave id 0..3; one wave handles one row

  for (int row = blockIdx.x * 4 + wid; row < nrows; row += gridDim.x * 4) {
    const float* xr = x + (size_t)row * D_DIM;
    float* ur = uout + (size_t)row * D_DIM;
    float lsum = 0.f;
#pragma unroll
    for (int q = 0; q < 4; ++q) {
      int d = lane + 64 * q;
      float xv = xr[d];
      float xc = fminf(fmaxf(xv, -BOUND), BOUND);
      bool inside = (xv >= -BOUND) && (xv <= BOUND);

      // count = #{k in [0,33): xc >= cw[k] + EPS}; 6 guarded binary-search steps
      int lo = 0, hi = K_BINS + 1;
#pragma unroll
      for (int it = 0; it < 6; ++it) {
        int mid = (lo + hi) >> 1;
        int midc = mid > K_BINS ? K_BINS : mid;
        float c = lcw[midc * D_DIM + d];
        bool valid = lo < hi;
        bool ge = valid && (xc >= c + EPS_);
        hi = (valid && !ge) ? mid : hi;
        lo = ge ? mid + 1 : lo;
      }
      int bin = lo - 1;
      bin = bin < 0 ? 0 : (bin > K_BINS - 1 ? K_BINS - 1 : bin);

      const BinParam* pp = tbl + (d * K_BINS + bin);
      float4 p0 = ((const float4*)pp)[0];
      float4 p1 = ((const float4*)pp)[1];
      float2 p2 = ((const float2*)pp)[4];  // llo, lhi

      float theta = (xc - p0.x) * p0.y;
      float il = p0.z;
      bool lobr = theta <= il;
      float t1 = il - theta;
      float t3 = 1.f - theta;
      float t4 = theta - il;
      float num_lo = p0.w * t1 + p1.y * theta;  // ya*(il-th) + wc*yc*th
      float den_lo = t1 + p1.x * theta;         // (il-th) + wc*th
      float num_hi = p1.y * t3 + p1.w * t4;     // wc*yc*(1-th) + wb*yb*(th-il)
      float den_hi = p1.x * t3 + p1.z * t4;     // wc*(1-th) + wb*(th-il)
      float num = lobr ? num_lo : num_hi;
      float den = lobr ? den_lo : den_hi;
      float ldn = lobr ? p2.x : p2.y;

      float uu = num / den;
      float lad = ldn - 2.f * __logf(fabsf(den));

      ur[d] = inside ? uu : xv;
      lsum += inside ? lad : 0.f;
    }
    // wave-level (64-lane) reduction of logabsdet
    lsum += __shfl_down(lsum, 32);
    lsum += __shfl_down(lsum, 16);
    lsum += __shfl_down(lsum, 8);
    lsum += __shfl_down(lsum, 4);
    lsum += __shfl_down(lsum, 2);
    lsum += __shfl_down(lsum, 1);
    if (lane == 0) ldout[row] = lsum;
  }
}

extern "C" void kernel_launch(void* const* d_in, const int* in_sizes, int n_in,
                              void* d_out, int out_size, void* d_ws, size_t ws_size,
                              hipStream_t stream) {
  const float* x  = (const float*)d_in[0];
  const float* uw = (const float*)d_in[1];
  const float* uh = (const float*)d_in[2];
  const float* ud = (const float*)d_in[3];
  const float* ul = (const float*)d_in[4];

  int B = in_sizes[0] / D_DIM;  // 32768

  float* out = (float*)d_out;
  float* uout = out;
  float* ldout = out + (size_t)B * D_DIM;

  BinParam* tbl = (BinParam*)d_ws;
  float* cw_g = (float*)((char*)d_ws + (size_t)D_DIM * K_BINS * sizeof(BinParam));

  spline_precompute<<<4, 64, 0, stream>>>(uw, uh, ud, ul, tbl, cw_g);
  spline_main<<<2048, 256, 0, stream>>>(x, tbl, cw_g, uout, ldout, B);
}

// Round 3
// 41.729 us; speedup vs baseline: 2.9223x; 2.9223x over previous
//
#include <hip/hip_runtime.h>
#include <math.h>

#define D_DIM 256
#define K_BINS 32

static constexpr float BOUND = 3.0f;
static constexpr float MIN_BIN_W = 1e-3f;
static constexpr float MIN_DERIV = 1e-3f;
static constexpr float MIN_LAMBDA = 0.025f;
static constexpr float EPS_ = 1e-6f;

__device__ __forceinline__ float softplusf_(float x) {
  return fmaxf(x, 0.0f) + log1pf(expf(-fabsf(x)));
}

// Entry: 8 f32 per (d,k): [icw][1/iw][lam][wc][wb][ya][yc][yb]
// One dim per 32-lane group; 8 dims per 256-thread block; 32 blocks.
__global__ void spline_precompute(const float* __restrict__ uw,
                                  const float* __restrict__ uh,
                                  const float* __restrict__ ud,
                                  const float* __restrict__ ul,
                                  float* __restrict__ tbl,
                                  float* __restrict__ cw_g) {
  int tid = threadIdx.x;
  int k = tid & 31;
  int d = blockIdx.x * 8 + (tid >> 5);

  float uwv = uw[d * K_BINS + k];
  float uhv = uh[d * K_BINS + k];
  float ulv = ul[d * K_BINS + k];
  float udv = (k < K_BINS - 1) ? ud[d * (K_BINS - 1) + k] : 0.0f;

  // 32-lane softmax stats
  float wm = uwv, hm = uhv;
  for (int o = 16; o; o >>= 1) {
    wm = fmaxf(wm, __shfl_xor(wm, o, 32));
    hm = fmaxf(hm, __shfl_xor(hm, o, 32));
  }
  float ew = expf(uwv - wm), eh = expf(uhv - hm);
  float ws = ew, hs = eh;
  for (int o = 16; o; o >>= 1) {
    ws += __shfl_xor(ws, o, 32);
    hs += __shfl_xor(hs, o, 32);
  }
  const float kfac = 1.0f - MIN_BIN_W * (float)K_BINS;  // same for W and H
  float sw = MIN_BIN_W + kfac * (ew / ws);
  float sh = MIN_BIN_W + kfac * (eh / hs);

  // inclusive 32-lane prefix sums
  float cws = sw, chs = sh;
  for (int o = 1; o < 32; o <<= 1) {
    float tw = __shfl_up(cws, o, 32);
    float th = __shfl_up(chs, o, 32);
    if (k >= o) { cws += tw; chs += th; }
  }
  const float scale = 2.0f * BOUND;
  float raw_w = scale * cws - BOUND;  // cum[k+1]
  float raw_h = scale * chs - BOUND;
  float upw = __shfl_up(raw_w, 1, 32);
  float uph = __shfl_up(raw_h, 1, 32);
  float cw_lo = (k == 0) ? -BOUND : upw;
  float ch_lo = (k == 0) ? -BOUND : uph;
  float cw_hi = (k == K_BINS - 1) ? BOUND : raw_w;
  float ch_hi = (k == K_BINS - 1) ? BOUND : raw_h;

  float iw = cw_hi - cw_lo;
  float ih = ch_hi - ch_lo;

  // derivs = [1, d_0..d_30, 1]; bin k uses (derivs[k], derivs[k+1])
  float dk = MIN_DERIV + softplusf_(udv);
  float dprev = __shfl_up(dk, 1, 32);
  float d1 = (k == K_BINS - 1) ? 1.0f : dk;
  float d0 = (k == 0) ? 1.0f : dprev;

  float sg = 1.0f / (1.0f + expf(-ulv));
  float lam = MIN_LAMBDA + (1.0f - 2.0f * MIN_LAMBDA) * sg;

  float wb = sqrtf(d0 / d1);
  float delta = ih / iw;
  float wc = (lam * d0 + (1.0f - lam) * wb * d1) / delta;
  float denom = (1.0f - lam) + lam * wb;
  float dyc = lam * wb * ih / denom;  // yc - ya
  float ya = ch_lo;

  float* e = tbl + (size_t)(d * K_BINS + k) * 8;
  e[0] = cw_lo;
  e[1] = 1.0f / iw;
  e[2] = lam;
  e[3] = wc;
  e[4] = wb;
  e[5] = ya;
  e[6] = ya + dyc;  // yc
  e[7] = ya + ih;   // yb
  cw_g[d * K_BINS + k] = cw_lo;
}

// Block: 512 threads = 8 waves; owns 32 dims (slice = blockIdx&7).
// Wave = 2 rows x 32 dims (half = lane>>5). Table fully LDS-resident.
__global__ __launch_bounds__(512) void spline_main(
    const float* __restrict__ x,
    const float* __restrict__ tbl,
    const float* __restrict__ cw_g,
    float* __restrict__ uout,
    float* __restrict__ ldout,
    int B) {
  __shared__ float lcw[32 * 33];    // [dim][k], stride 33
  __shared__ float lent[32 * 257];  // [dim][bin*8+f], stride 257

  int tid = threadIdx.x;
  int slice = blockIdx.x & 7;
  int d0 = slice * 32;

  for (int i = tid; i < 32 * 32; i += 512)
    lcw[(i >> 5) * 33 + (i & 31)] = cw_g[d0 * K_BINS + i];
  const float* src = tbl + (size_t)d0 * K_BINS * 8;
  for (int i = tid; i < 32 * 32 * 8; i += 512) {
    int j = i >> 3, f = i & 7;
    lent[(j >> 5) * 257 + (j & 31) * 8 + f] = src[i];
  }
  __syncthreads();

  int lane = tid & 63;
  int wid = tid >> 6;
  int half = lane >> 5;
  int dsl = lane & 31;
  int dglob = d0 + dsl;
  int wgidx = (blockIdx.x >> 3) * 8 + wid;  // [0,1024) within slice
  const int cwb = dsl * 33;
  const int enb = dsl * 257;
  int RP = B >> 1;  // row pairs

  for (int rp = wgidx; rp < RP; rp += 1024) {
    int row = 2 * rp + half;
    float xv = x[(size_t)row * D_DIM + dglob];
    float xc = fminf(fmaxf(xv, -BOUND), BOUND);
    bool inside = (xv >= -BOUND) && (xv <= BOUND);

    // largest j in [0,32) with xc >= cw[j]+EPS (else 0)
    int idx = 0;
#pragma unroll
    for (int st = 16; st >= 1; st >>= 1) {
      float c = lcw[cwb + idx + st];
      idx = (xc >= c + EPS_) ? idx + st : idx;
    }

    int eb = enb + idx * 8;
    float icw    = lent[eb + 0];
    float inv_iw = lent[eb + 1];
    float il     = lent[eb + 2];
    float wcv    = lent[eb + 3];
    float wbv    = lent[eb + 4];
    float ya     = lent[eb + 5];
    float yc     = lent[eb + 6];
    float yb     = lent[eb + 7];

    float theta = (xc - icw) * inv_iw;
    bool lo = theta <= il;
    float t1 = il - theta;
    float t3 = 1.0f - theta;
    float t4 = theta - il;
    float wcyc = wcv * yc;

    float num = lo ? (ya * t1 + wcyc * theta) : (wcyc * t3 + wbv * yb * t4);
    float den = lo ? (t1 + wcv * theta)       : (wcv * t3 + wbv * t4);
    float dnum = (lo ? (wcv * il * (yc - ya))
                     : (wbv * wcv * (1.0f - il) * (yb - yc))) * inv_iw;

    float uu = num / den;
    float lad = __logf(dnum) - 2.0f * __logf(fabsf(den));

    uout[(size_t)row * D_DIM + dglob] = inside ? uu : xv;
    float ls = inside ? lad : 0.0f;

    // 32-lane half-wave reduce; one atomic per (row, slice)
    ls += __shfl_down(ls, 16, 32);
    ls += __shfl_down(ls, 8, 32);
    ls += __shfl_down(ls, 4, 32);
    ls += __shfl_down(ls, 2, 32);
    ls += __shfl_down(ls, 1, 32);
    if (dsl == 0) atomicAdd(&ldout[row], ls);
  }
}

extern "C" void kernel_launch(void* const* d_in, const int* in_sizes, int n_in,
                              void* d_out, int out_size, void* d_ws, size_t ws_size,
                              hipStream_t stream) {
  const float* x  = (const float*)d_in[0];
  const float* uw = (const float*)d_in[1];
  const float* uh = (const float*)d_in[2];
  const float* ud = (const float*)d_in[3];
  const float* ul = (const float*)d_in[4];

  int B = in_sizes[0] / D_DIM;  // 32768

  float* out = (float*)d_out;
  float* uout = out;
  float* ldout = out + (size_t)B * D_DIM;

  float* tbl = (float*)d_ws;                                              // 256*32*8*4 = 256 KB
  float* cw_g = (float*)((char*)d_ws + (size_t)D_DIM * K_BINS * 8 * 4);   // 32 KB

  spline_precompute<<<32, 256, 0, stream>>>(uw, uh, ud, ul, tbl, cw_g);
  hipMemsetAsync(ldout, 0, (size_t)B * sizeof(float), stream);
  spline_main<<<1024, 512, 0, stream>>>(x, tbl, cw_g, uout, ldout, B);
}

// Round 4
// 39.379 us; speedup vs baseline: 3.0967x; 1.0597x over previous
//
#include <hip/hip_runtime.h>
#include <math.h>

#define D_DIM 256
#define K_BINS 32

static constexpr float BOUND = 3.0f;
static constexpr float MIN_BIN_W = 1e-3f;
static constexpr float MIN_DERIV = 1e-3f;
static constexpr float MIN_LAMBDA = 0.025f;
static constexpr float EPS_ = 1e-6f;

__device__ __forceinline__ float softplusf_(float x) {
  return fmaxf(x, 0.0f) + log1pf(expf(-fabsf(x)));
}

// Entry: 8 f32 per (d,k): [icw][1/iw][lam][wc][wb][ya][yc][yb]
// One dim per 32-lane group; 8 dims per 256-thread block; 32 blocks.
// Also zeroes ldout (so no hipMemsetAsync in the graph).
__global__ void spline_precompute(const float* __restrict__ uw,
                                  const float* __restrict__ uh,
                                  const float* __restrict__ ud,
                                  const float* __restrict__ ul,
                                  float* __restrict__ tbl,
                                  float* __restrict__ cw_g,
                                  float* __restrict__ ldout,
                                  int B) {
  int tid = threadIdx.x;
  int gtid = blockIdx.x * 256 + tid;
  // zero the logdet accumulator (stream-ordered before spline_main's atomics)
  for (int i = gtid; i < B; i += 32 * 256) ldout[i] = 0.0f;

  int k = tid & 31;
  int d = blockIdx.x * 8 + (tid >> 5);

  float uwv = uw[d * K_BINS + k];
  float uhv = uh[d * K_BINS + k];
  float ulv = ul[d * K_BINS + k];
  float udv = (k < K_BINS - 1) ? ud[d * (K_BINS - 1) + k] : 0.0f;

  // 32-lane softmax stats
  float wm = uwv, hm = uhv;
  for (int o = 16; o; o >>= 1) {
    wm = fmaxf(wm, __shfl_xor(wm, o, 32));
    hm = fmaxf(hm, __shfl_xor(hm, o, 32));
  }
  float ew = expf(uwv - wm), eh = expf(uhv - hm);
  float ws = ew, hs = eh;
  for (int o = 16; o; o >>= 1) {
    ws += __shfl_xor(ws, o, 32);
    hs += __shfl_xor(hs, o, 32);
  }
  const float kfac = 1.0f - MIN_BIN_W * (float)K_BINS;  // same for W and H
  float sw = MIN_BIN_W + kfac * (ew / ws);
  float sh = MIN_BIN_W + kfac * (eh / hs);

  // inclusive 32-lane prefix sums
  float cws = sw, chs = sh;
  for (int o = 1; o < 32; o <<= 1) {
    float tw = __shfl_up(cws, o, 32);
    float th = __shfl_up(chs, o, 32);
    if (k >= o) { cws += tw; chs += th; }
  }
  const float scale = 2.0f * BOUND;
  float raw_w = scale * cws - BOUND;  // cum[k+1]
  float raw_h = scale * chs - BOUND;
  float upw = __shfl_up(raw_w, 1, 32);
  float uph = __shfl_up(raw_h, 1, 32);
  float cw_lo = (k == 0) ? -BOUND : upw;
  float ch_lo = (k == 0) ? -BOUND : uph;
  float cw_hi = (k == K_BINS - 1) ? BOUND : raw_w;
  float ch_hi = (k == K_BINS - 1) ? BOUND : raw_h;

  float iw = cw_hi - cw_lo;
  float ih = ch_hi - ch_lo;

  // derivs = [1, d_0..d_30, 1]; bin k uses (derivs[k], derivs[k+1])
  float dk = MIN_DERIV + softplusf_(udv);
  float dprev = __shfl_up(dk, 1, 32);
  float d1 = (k == K_BINS - 1) ? 1.0f : dk;
  float d0 = (k == 0) ? 1.0f : dprev;

  float sg = 1.0f / (1.0f + expf(-ulv));
  float lam = MIN_LAMBDA + (1.0f - 2.0f * MIN_LAMBDA) * sg;

  float wb = sqrtf(d0 / d1);
  float delta = ih / iw;
  float wc = (lam * d0 + (1.0f - lam) * wb * d1) / delta;
  float denom = (1.0f - lam) + lam * wb;
  float dyc = lam * wb * ih / denom;  // yc - ya
  float ya = ch_lo;

  float* e = tbl + (size_t)(d * K_BINS + k) * 8;
  e[0] = cw_lo;
  e[1] = 1.0f / iw;
  e[2] = lam;
  e[3] = wc;
  e[4] = wb;
  e[5] = ya;
  e[6] = ya + dyc;  // yc
  e[7] = ya + ih;   // yb
  cw_g[d * K_BINS + k] = cw_lo;
}

// Block: 512 threads = 8 waves; owns 32 dims (slice = blockIdx&7).
// Wave = 2 rows x 32 dims (half = lane>>5). Table fully LDS-resident.
__global__ __launch_bounds__(512) void spline_main(
    const float* __restrict__ x,
    const float* __restrict__ tbl,
    const float* __restrict__ cw_g,
    float* __restrict__ uout,
    float* __restrict__ ldout,
    int B) {
  __shared__ float lcw[32 * 33];    // [dim][k], stride 33
  __shared__ float lent[32 * 257];  // [dim][bin*8+f], stride 257

  int tid = threadIdx.x;
  int slice = blockIdx.x & 7;
  int d0 = slice * 32;

  for (int i = tid; i < 32 * 32; i += 512)
    lcw[(i >> 5) * 33 + (i & 31)] = cw_g[d0 * K_BINS + i];
  const float* src = tbl + (size_t)d0 * K_BINS * 8;
  for (int i = tid; i < 32 * 32 * 8; i += 512) {
    int j = i >> 3, f = i & 7;
    lent[(j >> 5) * 257 + (j & 31) * 8 + f] = src[i];
  }
  __syncthreads();

  int lane = tid & 63;
  int wid = tid >> 6;
  int half = lane >> 5;
  int dsl = lane & 31;
  int dglob = d0 + dsl;
  int wgidx = (blockIdx.x >> 3) * 8 + wid;  // [0,1024) within slice
  const int cwb = dsl * 33;
  const int enb = dsl * 257;
  int RP = B >> 1;  // row pairs

  for (int rp = wgidx; rp < RP; rp += 1024) {
    int row = 2 * rp + half;
    float xv = x[(size_t)row * D_DIM + dglob];
    float xc = fminf(fmaxf(xv, -BOUND), BOUND);
    bool inside = (xv >= -BOUND) && (xv <= BOUND);

    // largest j in [0,32) with xc >= cw[j]+EPS (else 0)
    int idx = 0;
#pragma unroll
    for (int st = 16; st >= 1; st >>= 1) {
      float c = lcw[cwb + idx + st];
      idx = (xc >= c + EPS_) ? idx + st : idx;
    }

    int eb = enb + idx * 8;
    float icw    = lent[eb + 0];
    float inv_iw = lent[eb + 1];
    float il     = lent[eb + 2];
    float wcv    = lent[eb + 3];
    float wbv    = lent[eb + 4];
    float ya     = lent[eb + 5];
    float yc     = lent[eb + 6];
    float yb     = lent[eb + 7];

    float theta = (xc - icw) * inv_iw;
    bool lo = theta <= il;
    float t1 = il - theta;
    float t3 = 1.0f - theta;
    float t4 = theta - il;
    float wcyc = wcv * yc;

    float num = lo ? (ya * t1 + wcyc * theta) : (wcyc * t3 + wbv * yb * t4);
    float den = lo ? (t1 + wcv * theta)       : (wcv * t3 + wbv * t4);
    float dnum = (lo ? (wcv * il * (yc - ya))
                     : (wbv * wcv * (1.0f - il) * (yb - yc))) * inv_iw;

    float uu = num / den;
    float lad = __logf(dnum) - 2.0f * __logf(fabsf(den));

    uout[(size_t)row * D_DIM + dglob] = inside ? uu : xv;
    float ls = inside ? lad : 0.0f;

    // 32-lane half-wave reduce; one atomic per (row, slice)
    ls += __shfl_down(ls, 16, 32);
    ls += __shfl_down(ls, 8, 32);
    ls += __shfl_down(ls, 4, 32);
    ls += __shfl_down(ls, 2, 32);
    ls += __shfl_down(ls, 1, 32);
    if (dsl == 0) atomicAdd(&ldout[row], ls);
  }
}

extern "C" void kernel_launch(void* const* d_in, const int* in_sizes, int n_in,
                              void* d_out, int out_size, void* d_ws, size_t ws_size,
                              hipStream_t stream) {
  const float* x  = (const float*)d_in[0];
  const float* uw = (const float*)d_in[1];
  const float* uh = (const float*)d_in[2];
  const float* ud = (const float*)d_in[3];
  const float* ul = (const float*)d_in[4];

  int B = in_sizes[0] / D_DIM;  // 32768

  float* out = (float*)d_out;
  float* uout = out;
  float* ldout = out + (size_t)B * D_DIM;

  float* tbl = (float*)d_ws;                                              // 256*32*8*4 = 256 KB
  float* cw_g = (float*)((char*)d_ws + (size_t)D_DIM * K_BINS * 8 * 4);   // 32 KB

  spline_precompute<<<32, 256, 0, stream>>>(uw, uh, ud, ul, tbl, cw_g, ldout, B);
  spline_main<<<1024, 512, 0, stream>>>(x, tbl, cw_g, uout, ldout, B);
}

// Round 5
// 36.875 us; speedup vs baseline: 3.3070x; 1.0679x over previous
//
#include <hip/hip_runtime.h>
#include <math.h>
#include <stdint.h>

#define D_DIM 256
#define K_BINS 32
#define NCELL 512
#define NENT 34              // 32 bins + 2 sentinels
#define ENT_DW 12            // dwords per entry (48 B, 16B-aligned)
#define ENT_STRIDE 412       // dwords per dim in LDS (34*12 + 4 pad)
#define LIC_STRIDE 35        // floats per dim in LDS
#define LUT_BSTRIDE 516      // bytes per dim in LDS (512 + 4 pad)
#define SLICE 16             // dims per block

static constexpr float BOUND = 3.0f;
static constexpr float MIN_BIN_W = 1e-3f;
static constexpr float MIN_DERIV = 1e-3f;
static constexpr float MIN_LAMBDA = 0.025f;
static constexpr float EPS_ = 1e-6f;
static constexpr float CELL_W = 6.0f / NCELL;     // 0.01171875
static constexpr float CELL_S = NCELL / 6.0f;     // 85.333336f

__device__ __forceinline__ float softplusf_(float x) {
  return fmaxf(x, 0.0f) + log1pf(expf(-fabsf(x)));
}

// 32 blocks x 256 threads; block owns 8 dims (k = tid&31, dsub = tid>>5).
// Writes: tblg dense [d][34][12], licg dense [d][34] (= cw+eps, sentinels 1e30),
// lutg dense [d][512] u8, and zeroes ldout.
__global__ void spline_precompute(const float* __restrict__ uw,
                                  const float* __restrict__ uh,
                                  const float* __restrict__ ud,
                                  const float* __restrict__ ul,
                                  float* __restrict__ tblg,
                                  float* __restrict__ licg,
                                  uint8_t* __restrict__ lutg,
                                  float* __restrict__ ldout,
                                  int B) {
  __shared__ float cw_lds[8][32];

  int tid = threadIdx.x;
  int gtid = blockIdx.x * 256 + tid;
  for (int i = gtid; i < B; i += 32 * 256) ldout[i] = 0.0f;

  int k = tid & 31;
  int dsub = tid >> 5;
  int d = blockIdx.x * 8 + dsub;

  float uwv = uw[d * K_BINS + k];
  float uhv = uh[d * K_BINS + k];
  float ulv = ul[d * K_BINS + k];
  float udv = (k < K_BINS - 1) ? ud[d * (K_BINS - 1) + k] : 0.0f;

  // 32-lane softmax stats
  float wm = uwv, hm = uhv;
  for (int o = 16; o; o >>= 1) {
    wm = fmaxf(wm, __shfl_xor(wm, o, 32));
    hm = fmaxf(hm, __shfl_xor(hm, o, 32));
  }
  float ew = expf(uwv - wm), eh = expf(uhv - hm);
  float ws = ew, hs = eh;
  for (int o = 16; o; o >>= 1) {
    ws += __shfl_xor(ws, o, 32);
    hs += __shfl_xor(hs, o, 32);
  }
  const float kfac = 1.0f - MIN_BIN_W * (float)K_BINS;
  float sw = MIN_BIN_W + kfac * (ew / ws);
  float sh = MIN_BIN_W + kfac * (eh / hs);

  // inclusive 32-lane prefix sums
  float cws = sw, chs = sh;
  for (int o = 1; o < 32; o <<= 1) {
    float tw = __shfl_up(cws, o, 32);
    float th = __shfl_up(chs, o, 32);
    if (k >= o) { cws += tw; chs += th; }
  }
  const float scale = 2.0f * BOUND;
  float raw_w = scale * cws - BOUND;
  float raw_h = scale * chs - BOUND;
  float upw = __shfl_up(raw_w, 1, 32);
  float uph = __shfl_up(raw_h, 1, 32);
  float cw_lo = (k == 0) ? -BOUND : upw;
  float ch_lo = (k == 0) ? -BOUND : uph;
  float cw_hi = (k == K_BINS - 1) ? BOUND : raw_w;
  float ch_hi = (k == K_BINS - 1) ? BOUND : raw_h;

  float iw = cw_hi - cw_lo;
  float ih = ch_hi - ch_lo;

  float dk = MIN_DERIV + softplusf_(udv);
  float dprev = __shfl_up(dk, 1, 32);
  float d1 = (k == K_BINS - 1) ? 1.0f : dk;
  float d0 = (k == 0) ? 1.0f : dprev;

  float sg = 1.0f / (1.0f + expf(-ulv));
  float lam = MIN_LAMBDA + (1.0f - 2.0f * MIN_LAMBDA) * sg;

  float wb = sqrtf(d0 / d1);
  float delta = ih / iw;
  float wc = (lam * d0 + (1.0f - lam) * wb * d1) / delta;
  float denom = (1.0f - lam) + lam * wb;
  float dyc = lam * wb * ih / denom;   // yc - ya
  float dyb = ih - dyc;                // yb - yc
  float ya = ch_lo;
  float inv_iw = 1.0f / iw;

  float* e = tblg + (size_t)(d * NENT + k) * ENT_DW;
  e[0] = cw_lo;
  e[1] = inv_iw;
  e[2] = lam;
  e[3] = wc;
  e[4] = wb;
  e[5] = wc * (ya + dyc);   // wc*yc
  e[6] = wb * (ya + ih);    // wb*yb
  e[7] = ya;
  e[8] = log2f(wc * lam * dyc * inv_iw);            // L_lo
  e[9] = log2f(wc * wb * (1.0f - lam) * dyb * inv_iw); // L_hi
  e[10] = 0.0f;
  e[11] = 0.0f;
  licg[d * NENT + k] = cw_lo + EPS_;
  cw_lds[dsub][k] = cw_lo;

  // sentinel entries k=32,33: icw/lic = +inf-ish, rest 0
  if (tid < 8 * 2 * ENT_DW) {  // 192 threads
    int dim = tid / (2 * ENT_DW);
    int r = tid - dim * (2 * ENT_DW);
    int ks = 32 + r / ENT_DW;
    int f = r - (r / ENT_DW) * ENT_DW;
    int dd = blockIdx.x * 8 + dim;
    tblg[((size_t)(dd * NENT + ks)) * ENT_DW + f] = (f == 0) ? 1e30f : 0.0f;
  }
  if (tid < 16) {
    int dim = tid >> 1;
    int ks = 32 + (tid & 1);
    licg[(blockIdx.x * 8 + dim) * NENT + ks] = 1e30f;
  }
  __syncthreads();

  // LUT build: 8 dims x 512 cells, 16 cells/thread
  for (int rep = 0; rep < 16; ++rep) {
    int idx = rep * 256 + tid;
    int dim = idx >> 9;
    int c = idx & (NCELL - 1);
    float L = fmaf((float)c, CELL_W, -BOUND) - 1e-5f;
    int j = 0;
#pragma unroll
    for (int st = 16; st >= 1; st >>= 1) {
      float cv = cw_lds[dim][j + st];
      j = (L >= cv + EPS_) ? j + st : j;
    }
    lutg[(blockIdx.x * 8 + dim) * NCELL + c] = (uint8_t)j;
  }
}

// 1024 blocks x 512 threads (8 waves). Block owns 16 dims (slice = blk&15).
// Wave = 4 rows x 16 dims. LUT + refine (exact) + 12-dword entry in LDS.
__global__ __launch_bounds__(512, 8) void spline_main(
    const float* __restrict__ x,
    const float* __restrict__ tblg,
    const float* __restrict__ licg,
    const uint8_t* __restrict__ lutg,
    float* __restrict__ uout,
    float* __restrict__ ldout,
    int B) {
  __shared__ float lent[SLICE * ENT_STRIDE];     // 26368 B
  __shared__ float lic[SLICE * LIC_STRIDE];      // 2240 B
  __shared__ uint8_t lutb[SLICE * LUT_BSTRIDE];  // 8256 B

  int tid = threadIdx.x;
  int slice = blockIdx.x & 15;
  int group = blockIdx.x >> 4;   // 0..63
  int d0 = slice * SLICE;

  // stage entries (dense [dim][34][12] -> padded stride 412)
  const float* esrc = tblg + (size_t)d0 * NENT * ENT_DW;
  for (int i = tid; i < SLICE * NENT * ENT_DW; i += 512) {
    int dim = i / (NENT * ENT_DW);
    int rem = i - dim * (NENT * ENT_DW);
    lent[dim * ENT_STRIDE + rem] = esrc[i];
  }
  // stage lic (dense [dim][34] -> stride 35)
  const float* lsrc = licg + (size_t)d0 * NENT;
  for (int i = tid; i < SLICE * NENT; i += 512) {
    int dim = i / NENT;
    int kk = i - dim * NENT;
    lic[dim * LIC_STRIDE + kk] = lsrc[i];
  }
  // stage LUT as dwords (dense [dim][512]B -> stride 516B)
  const uint32_t* lut32 = (const uint32_t*)(lutg + (size_t)d0 * NCELL);
  uint32_t* lutb32 = (uint32_t*)lutb;
  for (int i = tid; i < SLICE * (NCELL / 4); i += 512) {
    int dim = i >> 7;
    int w = i & 127;
    lutb32[dim * (LUT_BSTRIDE / 4) + w] = lut32[i];
  }
  __syncthreads();

  int lane = tid & 63;
  int wid = tid >> 6;
  int r4 = lane >> 4;
  int dsl = lane & 15;

  int row0 = group * 32 + wid * 4 + r4;
  size_t base = (size_t)row0 * D_DIM + d0 + dsl;
  const int entb = dsl * ENT_STRIDE;
  const int licb = dsl * LIC_STRIDE;
  const int lutbase = dsl * LUT_BSTRIDE;

  int niter = B >> 11;  // B / 2048
  for (int it = 0; it < niter; ++it) {
    int row = row0 + (it << 11);
    size_t gidx = base + ((size_t)it << 11) * D_DIM;

    float xv = x[gidx];
    float xc = fminf(fmaxf(xv, -BOUND), BOUND);   // v_med3
    bool inside = fabsf(xv) <= BOUND;

    // cell -> LUT -> 2 exact refine steps
    float cf = fmaf(xc, CELL_S, (float)(NCELL / 2));
    int c = (int)cf;
    c = min(c, NCELL - 1);
    int ilut = (int)lutb[lutbase + c];

    float c1 = lic[licb + ilut + 1];   // cw+eps, sentinel-safe
    float c2 = lic[licb + ilut + 2];
    int idx = ilut + (xc >= c1 ? 1 : 0) + (xc >= c2 ? 1 : 0);

    int eb = entb + idx * ENT_DW;
    float4 A = *reinterpret_cast<const float4*>(&lent[eb]);      // icw,inv_iw,il,wc
    float4 Bv = *reinterpret_cast<const float4*>(&lent[eb + 4]); // wb,wcyc,wbyb,ya
    float2 Lv = *reinterpret_cast<const float2*>(&lent[eb + 8]); // L_lo,L_hi

    float icw = A.x, inv_iw = A.y, il = A.z, wcv = A.w;
    float wbv = Bv.x, wcyc = Bv.y, wbyb = Bv.z, ya = Bv.w;

    float theta = (xc - icw) * inv_iw;
    bool lo = theta <= il;
    float t1 = il - theta;
    float t3 = 1.0f - theta;

    float n0 = lo ? ya : wcyc;
    float n1 = lo ? wcyc : wbyb;
    float p  = lo ? t1 : t3;
    float q  = lo ? theta : -t1;
    float dd0 = lo ? 1.0f : wcv;
    float dd1 = lo ? wcv : wbv;
    float Ls = lo ? Lv.x : Lv.y;

    float num = fmaf(n1, q, n0 * p);
    float den = fmaf(dd1, q, dd0 * p);
    float r = __builtin_amdgcn_rcpf(den);
    float uu = num * r;
    float lad2 = fmaf(-2.0f, __builtin_amdgcn_logf(den), Ls);  // log2 units

    uout[gidx] = inside ? uu : xv;
    float ls = inside ? lad2 : 0.0f;

    // width-16 reduce over dims, then one fire-and-forget atomic per row
    ls += __shfl_down(ls, 8, 16);
    ls += __shfl_down(ls, 4, 16);
    ls += __shfl_down(ls, 2, 16);
    ls += __shfl_down(ls, 1, 16);
    if (dsl == 0) atomicAdd(&ldout[row], ls * 0.69314718056f);
  }
}

extern "C" void kernel_launch(void* const* d_in, const int* in_sizes, int n_in,
                              void* d_out, int out_size, void* d_ws, size_t ws_size,
                              hipStream_t stream) {
  const float* x  = (const float*)d_in[0];
  const float* uw = (const float*)d_in[1];
  const float* uh = (const float*)d_in[2];
  const float* ud = (const float*)d_in[3];
  const float* ul = (const float*)d_in[4];

  int B = in_sizes[0] / D_DIM;  // 32768

  float* out = (float*)d_out;
  float* uout = out;
  float* ldout = out + (size_t)B * D_DIM;

  char* ws = (char*)d_ws;
  float* tblg = (float*)ws;                                  // 256*34*12*4 = 417792 B
  float* licg = (float*)(ws + 417792);                       // 256*34*4   = 34816 B
  uint8_t* lutg = (uint8_t*)(ws + 417792 + 34816);           // 256*512    = 131072 B

  spline_precompute<<<32, 256, 0, stream>>>(uw, uh, ud, ul, tblg, licg, lutg, ldout, B);
  spline_main<<<1024, 512, 0, stream>>>(x, tblg, licg, lutg, uout, ldout, B);
}